// Round 3
// baseline (145.044 us; speedup 1.0000x reference)
//
#include <hip/hip_runtime.h>
#include <math.h>

#define VD 256
#define PAIR_BYTES (VD * VD * VD * 4UL)   // one uint (bf16 pair) per voxel

// P layout (floats): [0..8] M row-major, [9..11] src,
//                    [12..17] bounds xlo,xhi,ylo,yhi,zlo,zhi (integer-valued)

__device__ inline unsigned short f2bf(float f) {   // round-to-nearest-even
    unsigned int u = __float_as_uint(f);
    u += 0x7FFFu + ((u >> 16) & 1u);
    return (unsigned short)(u >> 16);
}

// ---------------------------------------------------------------------------
// Setup: 1 thread computes M = sdd * ext[:3,:3] @ k_inv, src, and the voxel
// AABB reachable by the ray cone (for transpose tile skipping).
// ---------------------------------------------------------------------------
__device__ inline void invert4x4(const float* m, float* inv) {
    inv[0]  =  m[5]*m[10]*m[15] - m[5]*m[11]*m[14] - m[9]*m[6]*m[15] + m[9]*m[7]*m[14] + m[13]*m[6]*m[11] - m[13]*m[7]*m[10];
    inv[4]  = -m[4]*m[10]*m[15] + m[4]*m[11]*m[14] + m[8]*m[6]*m[15] - m[8]*m[7]*m[14] - m[12]*m[6]*m[11] + m[12]*m[7]*m[10];
    inv[8]  =  m[4]*m[9]*m[15]  - m[4]*m[11]*m[13] - m[8]*m[5]*m[15] + m[8]*m[7]*m[13] + m[12]*m[5]*m[11] - m[12]*m[7]*m[9];
    inv[12] = -m[4]*m[9]*m[14]  + m[4]*m[10]*m[13] + m[8]*m[5]*m[14] - m[8]*m[6]*m[13] - m[12]*m[5]*m[10] + m[12]*m[6]*m[9];
    inv[1]  = -m[1]*m[10]*m[15] + m[1]*m[11]*m[14] + m[9]*m[2]*m[15] - m[9]*m[3]*m[14] - m[13]*m[2]*m[11] + m[13]*m[3]*m[10];
    inv[5]  =  m[0]*m[10]*m[15] - m[0]*m[11]*m[14] - m[8]*m[2]*m[15] + m[8]*m[3]*m[14] + m[12]*m[2]*m[11] - m[12]*m[3]*m[10];
    inv[9]  = -m[0]*m[9]*m[15]  + m[0]*m[11]*m[13] + m[8]*m[1]*m[15] - m[8]*m[3]*m[13] - m[12]*m[1]*m[11] + m[12]*m[3]*m[9];
    inv[13] =  m[0]*m[9]*m[14]  - m[0]*m[10]*m[13] - m[8]*m[1]*m[14] + m[8]*m[2]*m[13] + m[12]*m[1]*m[10] - m[12]*m[2]*m[9];
    inv[2]  =  m[1]*m[6]*m[15]  - m[1]*m[7]*m[14]  - m[5]*m[2]*m[15] + m[5]*m[3]*m[14] + m[13]*m[2]*m[7]  - m[13]*m[3]*m[6];
    inv[6]  = -m[0]*m[6]*m[15]  + m[0]*m[7]*m[14]  + m[4]*m[2]*m[15] - m[4]*m[3]*m[14] - m[12]*m[2]*m[7]  + m[12]*m[3]*m[6];
    inv[10] =  m[0]*m[5]*m[15]  - m[0]*m[7]*m[13]  - m[4]*m[1]*m[15] + m[4]*m[3]*m[13] + m[12]*m[1]*m[7]  - m[12]*m[3]*m[5];
    inv[14] = -m[0]*m[5]*m[14]  + m[0]*m[6]*m[13]  + m[4]*m[1]*m[14] - m[4]*m[2]*m[13] - m[12]*m[1]*m[6]  + m[12]*m[2]*m[5];
    inv[3]  = -m[1]*m[6]*m[11]  + m[1]*m[7]*m[10]  + m[5]*m[2]*m[11] - m[5]*m[3]*m[10] - m[9]*m[2]*m[7]   + m[9]*m[3]*m[6];
    inv[7]  =  m[0]*m[6]*m[11]  - m[0]*m[7]*m[10]  - m[4]*m[2]*m[11] + m[4]*m[3]*m[10] + m[8]*m[2]*m[7]   - m[8]*m[3]*m[6];
    inv[11] = -m[0]*m[5]*m[11]  + m[0]*m[7]*m[9]   + m[4]*m[1]*m[11] - m[4]*m[3]*m[9]  - m[8]*m[1]*m[7]   + m[8]*m[3]*m[5];
    inv[15] =  m[0]*m[5]*m[10]  - m[0]*m[6]*m[9]   - m[4]*m[1]*m[10] + m[4]*m[2]*m[9]  + m[8]*m[1]*m[6]   - m[8]*m[2]*m[5];
    float det = m[0]*inv[0] + m[1]*inv[4] + m[2]*inv[8] + m[3]*inv[12];
    float rdet = 1.0f / det;
    for (int i = 0; i < 16; i++) inv[i] *= rdet;
}

__global__ void setup_k(const float* __restrict__ iso,
                        const float* __restrict__ rt,
                        const float* __restrict__ kinv,
                        const float* __restrict__ sdd,
                        const float* __restrict__ rot,
                        const float* __restrict__ xyz,
                        const int* __restrict__ pH,
                        const int* __restrict__ pW,
                        float* __restrict__ P) {
    if (threadIdx.x != 0 || blockIdx.x != 0) return;
    float m[16];
    for (int i = 0; i < 16; i++) m[i] = rt[i];
    float minv[16];
    invert4x4(m, minv);
    float c0 = minv[0]*iso[0] + minv[1]*iso[1] + minv[2]*iso[2]  + minv[3];
    float c1 = minv[4]*iso[0] + minv[5]*iso[1] + minv[6]*iso[2]  + minv[7];
    float c2 = minv[8]*iso[0] + minv[9]*iso[1] + minv[10]*iso[2] + minv[11];
    float wx = rot[0], wy = rot[1], wz = rot[2];
    float th2 = wx*wx + wy*wy + wz*wz;
    float th = sqrtf(th2);
    float Ac, Bc;
    if (th < 1e-6f) { Ac = 1.0f - th2 / 6.0f; Bc = 0.5f - th2 / 24.0f; }
    else            { Ac = sinf(th) / th;     Bc = (1.0f - cosf(th)) / th2; }
    float R[9];
    R[0] = 1.0f + Bc * (-(wy*wy + wz*wz));
    R[1] = Ac * (-wz) + Bc * (wx*wy);
    R[2] = Ac * ( wy) + Bc * (wx*wz);
    R[3] = Ac * ( wz) + Bc * (wx*wy);
    R[4] = 1.0f + Bc * (-(wx*wx + wz*wz));
    R[5] = Ac * (-wx) + Bc * (wy*wz);
    R[6] = Ac * (-wy) + Bc * (wx*wz);
    R[7] = Ac * ( wx) + Bc * (wy*wz);
    R[8] = 1.0f + Bc * (-(wx*wx + wy*wy));
    float tx = R[0]*xyz[0] + R[1]*xyz[1] + R[2]*xyz[2];
    float ty = R[3]*xyz[0] + R[4]*xyz[1] + R[5]*xyz[2];
    float tz = R[6]*xyz[0] + R[7]*xyz[1] + R[8]*xyz[2];
    float pt0 = c0 + tx - (R[0]*c0 + R[1]*c1 + R[2]*c2);
    float pt1 = c1 + ty - (R[3]*c0 + R[4]*c1 + R[5]*c2);
    float pt2 = c2 + tz - (R[6]*c0 + R[7]*c1 + R[8]*c2);
    float E[12];
    for (int i = 0; i < 3; i++) {
        for (int j = 0; j < 3; j++)
            E[i*4+j] = rt[i*4+0]*R[0*3+j] + rt[i*4+1]*R[1*3+j] + rt[i*4+2]*R[2*3+j];
        E[i*4+3] = rt[i*4+0]*pt0 + rt[i*4+1]*pt1 + rt[i*4+2]*pt2 + rt[i*4+3];
    }
    float s = sdd[0];
    float M[9];
    for (int i = 0; i < 3; i++)
        for (int j = 0; j < 3; j++)
            M[i*3+j] = s * (E[i*4+0]*kinv[0*3+j] + E[i*4+1]*kinv[1*3+j] + E[i*4+2]*kinv[2*3+j]);
    for (int i = 0; i < 9; i++) P[i] = M[i];
    float src3[3] = {E[3], E[7], E[11]};
    P[9] = src3[0]; P[10] = src3[1]; P[11] = src3[2];

    // Voxel AABB of all samples: g linear in (u,v) -> extremes at corners;
    // sample coord range per pixel is [s+min(0,g), s+max(0,g)] over t in [0,1].
    float W = (float)pW[0], H = (float)pH[0];
    float us[2] = {0.5f, W - 0.5f};
    float vs[2] = {0.5f, H - 0.5f};
    for (int a = 0; a < 3; a++) {
        float gmin = 1e30f, gmax = -1e30f;
        for (int i = 0; i < 2; i++)
            for (int j = 0; j < 2; j++) {
                float g = M[a*3+0]*us[i] + M[a*3+1]*vs[j] + M[a*3+2];
                gmin = fminf(gmin, g); gmax = fmaxf(gmax, g);
            }
        float sa = src3[a];
        float lo = sa + fminf(0.0f, gmin);
        float hi = sa + fmaxf(0.0f, gmax);
        int loi = (int)floorf(lo) - 4;
        int hii = (int)ceilf(hi) + 5;
        loi = min(max(loi, 0), VD - 1);
        hii = min(max(hii, 0), VD - 1);
        P[12 + 2*a] = (float)loi;
        P[13 + 2*a] = (float)hii;
    }
}

// ---------------------------------------------------------------------------
// Transpose: Tp[z][y][x] = (bf16 vol[x][y][z]) | (bf16 vol[x+1][y][z] << 16)
// Tiles of 64(x) x 32(z) per y; tiles fully outside the sampled AABB skip.
// grid = (4 x-tiles, 8 z-tiles, 256 y), block = 256
// ---------------------------------------------------------------------------
__global__ __launch_bounds__(256)
void transpose_k(const float* __restrict__ in, unsigned int* __restrict__ Tp,
                 const float* __restrict__ P) {
    const int x0 = blockIdx.x * 64;
    const int z0 = blockIdx.y * 32;
    const int y  = blockIdx.z;
    const int xlo = (int)P[12], xhi = (int)P[13];
    const int ylo = (int)P[14], yhi = (int)P[15];
    const int zlo = (int)P[16], zhi = (int)P[17];
    // Skipped tiles are never read with nonzero weight; zero-weight reads of
    // poison are finite and multiply to exactly 0.
    if (x0 + 63 < xlo || x0 > xhi || y < ylo || y > yhi ||
        z0 + 31 < zlo || z0 > zhi) return;

    __shared__ unsigned short tile[32][68];   // [z][x], col 64 = x halo
    const int t = threadIdx.x;
    {
        const int zq = t & 7;          // float4 slot along z
        const int xl = t >> 3;         // 0..31
        #pragma unroll
        for (int i = 0; i < 2; i++) {
            int xr = xl + 32 * i;      // 0..63
            const float4 f = *(const float4*)(in + (((size_t)(x0 + xr)) << 16) + (y << 8) + z0 + 4*zq);
            tile[4*zq+0][xr] = f2bf(f.x);
            tile[4*zq+1][xr] = f2bf(f.y);
            tile[4*zq+2][xr] = f2bf(f.z);
            tile[4*zq+3][xr] = f2bf(f.w);
        }
        if (t < 8) {                   // halo row x0+64 (clamped)
            int xs = min(x0 + 64, VD - 1);
            const float4 f = *(const float4*)(in + (((size_t)xs) << 16) + (y << 8) + z0 + 4*t);
            tile[4*t+0][64] = f2bf(f.x);
            tile[4*t+1][64] = f2bf(f.y);
            tile[4*t+2][64] = f2bf(f.z);
            tile[4*t+3][64] = f2bf(f.w);
        }
    }
    __syncthreads();
    {
        const int xq = t & 15;         // 4-x group
        const int zl = t >> 4;         // 0..15
        #pragma unroll
        for (int i = 0; i < 2; i++) {
            int zr = zl + 16 * i;      // 0..31
            unsigned int a0 = tile[zr][4*xq+0];
            unsigned int a1 = tile[zr][4*xq+1];
            unsigned int a2 = tile[zr][4*xq+2];
            unsigned int a3 = tile[zr][4*xq+3];
            unsigned int a4 = tile[zr][4*xq+4];
            uint4 o;
            o.x = a0 | (a1 << 16);
            o.y = a1 | (a2 << 16);
            o.z = a2 | (a3 << 16);
            o.w = a3 | (a4 << 16);
            *(uint4*)(Tp + (((size_t)(z0 + zr)) << 16) + (y << 8) + x0 + 4*xq) = o;
        }
    }
}

// ---------------------------------------------------------------------------
// Render from paired layout: 4 aligned dword loads per sample.
// ---------------------------------------------------------------------------
__global__ __launch_bounds__(256)
void render_pair(const unsigned int* __restrict__ Tp, const float* __restrict__ P,
                 const int* __restrict__ pW, const int* __restrict__ pN,
                 float* __restrict__ out, int total) {
    int tid = blockIdx.x * 256 + threadIdx.x;
    if (tid >= total) return;
    const int W = pW[0];
    const int N = pN[0];
    int w = tid % W;
    int h = tid / W;
    float u = (float)w + 0.5f;
    float v = (float)h + 0.5f;

    float m0 = P[0], m1 = P[1], m2 = P[2];
    float m3 = P[3], m4 = P[4], m5 = P[5];
    float m6 = P[6], m7 = P[7], m8 = P[8];
    float sx = P[9], sy = P[10], sz = P[11];

    float gx = m0*u + m1*v + m2;
    float gy = m3*u + m4*v + m5;
    float gz = m6*u + m7*v + m8;
    float len = sqrtf(gx*gx + gy*gy + gz*gz);
    float invN = 1.0f / (float)N;

    // Conservative slab clip; weights still gate correctness.
    float t0 = 0.0f, t1 = 1.0f;
    {
        float s3[3] = {sx, sy, sz};
        float g3[3] = {gx, gy, gz};
        for (int a = 0; a < 3; a++) {
            float g = g3[a], s = s3[a];
            if (fabsf(g) > 1e-20f) {
                float ta = (-1.0f - s) / g;
                float tb = ((float)VD - s) / g;
                float lo = fminf(ta, tb), hi = fmaxf(ta, tb);
                t0 = fmaxf(t0, lo);
                t1 = fminf(t1, hi);
            } else if (s <= -1.0f || s >= (float)VD) {
                t1 = -1.0f;
            }
        }
    }
    int k0 = (int)floorf(t0 * (float)N - 0.5f) - 1;
    int k1 = (int)ceilf (t1 * (float)N - 0.5f) + 1;
    if (k0 < 0) k0 = 0;
    if (k1 > N - 1) k1 = N - 1;

    float acc = 0.0f;
    #pragma unroll 2
    for (int k = k0; k <= k1; k++) {
        float t = ((float)k + 0.5f) * invN;
        float x = fmaf(t, gx, sx);
        float y = fmaf(t, gy, sy);
        float z = fmaf(t, gz, sz);

        float fx = floorf(x); int ix = (int)fx; float ax = x - fx;
        float fy = floorf(y); int iy = (int)fy; float ay = y - fy;
        float fz = floorf(z); int iz = (int)fz; float az = z - fz;

        // x: pair-shifted weights (validity folded in)
        float wx0v = ((unsigned)ix       < (unsigned)VD) ? (1.0f - ax) : 0.0f;
        float wx1v = ((unsigned)(ix + 1) < (unsigned)VD) ? ax : 0.0f;
        int bx = min(max(ix, 0), VD - 1);
        int sxi = ix - bx;                 // 0 interior, -1 left edge, else OOB
        float w0p = (sxi == 0) ? wx0v : ((sxi == -1) ? wx1v : 0.0f);
        float w1p = (sxi == 0) ? wx1v : 0.0f;

        float wy0 = ((unsigned)iy       < (unsigned)VD) ? (1.0f - ay) : 0.0f;
        float wy1 = ((unsigned)(iy + 1) < (unsigned)VD) ? ay : 0.0f;
        float wz0 = ((unsigned)iz       < (unsigned)VD) ? (1.0f - az) : 0.0f;
        float wz1 = ((unsigned)(iz + 1) < (unsigned)VD) ? az : 0.0f;

        int iy0 = min(max(iy, 0), VD - 1), iy1 = min(max(iy + 1, 0), VD - 1);
        int iz0 = min(max(iz, 0), VD - 1), iz1 = min(max(iz + 1, 0), VD - 1);

        int i00 = (iz0 << 16) + (iy0 << 8) + bx;
        int i01 = i00 + ((iy1 - iy0) << 8);
        int i10 = i00 + ((iz1 - iz0) << 16);
        int i11 = i10 + ((iy1 - iy0) << 8);

        unsigned int p00 = Tp[i00];
        unsigned int p01 = Tp[i01];
        unsigned int p10 = Tp[i10];
        unsigned int p11 = Tp[i11];

        float f00a = __uint_as_float(p00 << 16), f00b = __uint_as_float(p00 & 0xFFFF0000u);
        float f01a = __uint_as_float(p01 << 16), f01b = __uint_as_float(p01 & 0xFFFF0000u);
        float f10a = __uint_as_float(p10 << 16), f10b = __uint_as_float(p10 & 0xFFFF0000u);
        float f11a = __uint_as_float(p11 << 16), f11b = __uint_as_float(p11 & 0xFFFF0000u);

        float cx00 = fmaf(f00a, w0p, f00b * w1p);   // (z0,y0)
        float cx01 = fmaf(f01a, w0p, f01b * w1p);   // (z0,y1)
        float cx10 = fmaf(f10a, w0p, f10b * w1p);   // (z1,y0)
        float cx11 = fmaf(f11a, w0p, f11b * w1p);   // (z1,y1)

        float cy0 = fmaf(cx00, wy0, cx01 * wy1);
        float cy1 = fmaf(cx10, wy0, cx11 * wy1);
        acc = fmaf(cy0, wz0, acc);
        acc = fmaf(cy1, wz1, acc);
    }
    out[tid] = acc * len * invN;
}

// ---------------------------------------------------------------------------
// Fallback: direct fp32 render from original layout (if ws too small).
// ---------------------------------------------------------------------------
__global__ __launch_bounds__(256)
void render_direct(const float* __restrict__ vol, const float* __restrict__ P,
                   const int* __restrict__ pW, const int* __restrict__ pN,
                   float* __restrict__ out, int total) {
    int tid = blockIdx.x * 256 + threadIdx.x;
    if (tid >= total) return;
    const int W = pW[0];
    const int N = pN[0];
    int w = tid % W;
    int h = tid / W;
    float u = (float)w + 0.5f;
    float v = (float)h + 0.5f;
    float m0 = P[0], m1 = P[1], m2 = P[2];
    float m3 = P[3], m4 = P[4], m5 = P[5];
    float m6 = P[6], m7 = P[7], m8 = P[8];
    float sx = P[9], sy = P[10], sz = P[11];
    float gx = m0*u + m1*v + m2;
    float gy = m3*u + m4*v + m5;
    float gz = m6*u + m7*v + m8;
    float len = sqrtf(gx*gx + gy*gy + gz*gz);
    float invN = 1.0f / (float)N;
    float t0 = 0.0f, t1 = 1.0f;
    {
        float s3[3] = {sx, sy, sz};
        float g3[3] = {gx, gy, gz};
        for (int a = 0; a < 3; a++) {
            float g = g3[a], s = s3[a];
            if (fabsf(g) > 1e-20f) {
                float ta = (-1.0f - s) / g;
                float tb = ((float)VD - s) / g;
                float lo = fminf(ta, tb), hi = fmaxf(ta, tb);
                t0 = fmaxf(t0, lo);
                t1 = fminf(t1, hi);
            } else if (s <= -1.0f || s >= (float)VD) {
                t1 = -1.0f;
            }
        }
    }
    int k0 = (int)floorf(t0 * (float)N - 0.5f) - 1;
    int k1 = (int)ceilf (t1 * (float)N - 0.5f) + 1;
    if (k0 < 0) k0 = 0;
    if (k1 > N - 1) k1 = N - 1;
    float acc = 0.0f;
    for (int k = k0; k <= k1; k++) {
        float t = ((float)k + 0.5f) * invN;
        float x = fmaf(t, gx, sx);
        float y = fmaf(t, gy, sy);
        float z = fmaf(t, gz, sz);
        float fx = floorf(x); int ix = (int)fx; float ax = x - fx;
        float fy = floorf(y); int iy = (int)fy; float ay = y - fy;
        float fz = floorf(z); int iz = (int)fz; float az = z - fz;
        float wx0 = ((unsigned)ix       < (unsigned)VD) ? (1.0f - ax) : 0.0f;
        float wx1 = ((unsigned)(ix + 1) < (unsigned)VD) ? ax : 0.0f;
        float wy0 = ((unsigned)iy       < (unsigned)VD) ? (1.0f - ay) : 0.0f;
        float wy1 = ((unsigned)(iy + 1) < (unsigned)VD) ? ay : 0.0f;
        float wz0 = ((unsigned)iz       < (unsigned)VD) ? (1.0f - az) : 0.0f;
        float wz1 = ((unsigned)(iz + 1) < (unsigned)VD) ? az : 0.0f;
        int ix0 = min(max(ix, 0), VD - 1), ix1 = min(max(ix + 1, 0), VD - 1);
        int iy0 = min(max(iy, 0), VD - 1), iy1 = min(max(iy + 1, 0), VD - 1);
        int iz0 = min(max(iz, 0), VD - 1), iz1 = min(max(iz + 1, 0), VD - 1);
        int X0 = ix0 << 16, X1 = ix1 << 16;
        int Y0 = iy0 << 8,  Y1 = iy1 << 8;
        float v000 = vol[X0 + Y0 + iz0];
        float v001 = vol[X0 + Y0 + iz1];
        float v010 = vol[X0 + Y1 + iz0];
        float v011 = vol[X0 + Y1 + iz1];
        float v100 = vol[X1 + Y0 + iz0];
        float v101 = vol[X1 + Y0 + iz1];
        float v110 = vol[X1 + Y1 + iz0];
        float v111 = vol[X1 + Y1 + iz1];
        float c00 = fmaf(v000, wz0, v001 * wz1);
        float c01 = fmaf(v010, wz0, v011 * wz1);
        float c10 = fmaf(v100, wz0, v101 * wz1);
        float c11 = fmaf(v110, wz0, v111 * wz1);
        float c0  = fmaf(c00, wy0, c01 * wy1);
        float c1  = fmaf(c10, wy0, c11 * wy1);
        acc += fmaf(c0, wx0, c1 * wx1);
    }
    out[tid] = acc * len * invN;
}

extern "C" void kernel_launch(void* const* d_in, const int* in_sizes, int n_in,
                              void* d_out, int out_size, void* d_ws, size_t ws_size,
                              hipStream_t stream) {
    const float* vol  = (const float*)d_in[0];
    const float* iso  = (const float*)d_in[1];
    const float* rt   = (const float*)d_in[2];
    const float* kinv = (const float*)d_in[3];
    const float* sdd  = (const float*)d_in[4];
    const float* rot  = (const float*)d_in[5];
    const float* xyz  = (const float*)d_in[6];
    const int* pH = (const int*)d_in[7];
    const int* pW = (const int*)d_in[8];
    const int* pN = (const int*)d_in[9];
    float* out = (float*)d_out;
    int total = out_size;

    if (ws_size >= PAIR_BYTES + 256) {
        unsigned int* Tp = (unsigned int*)d_ws;
        float* P = (float*)((char*)d_ws + PAIR_BYTES);
        setup_k<<<1, 64, 0, stream>>>(iso, rt, kinv, sdd, rot, xyz, pH, pW, P);
        transpose_k<<<dim3(4, 8, 256), 256, 0, stream>>>(vol, Tp, P);
        render_pair<<<(total + 255) / 256, 256, 0, stream>>>(Tp, P, pW, pN, out, total);
    } else {
        float* P = (float*)d_ws;
        setup_k<<<1, 64, 0, stream>>>(iso, rt, kinv, sdd, rot, xyz, pH, pW, P);
        render_direct<<<(total + 255) / 256, 256, 0, stream>>>(vol, P, pW, pN, out, total);
    }
}

// Round 4
// 142.931 us; speedup vs baseline: 1.0148x; 1.0148x over previous
//
#include <hip/hip_runtime.h>
#include <math.h>

#define VD 256
#define PAIR_BYTES (VD * VD * VD * 4UL)   // one uint (bf16 pair) per voxel

__device__ inline unsigned short f2bf(float f) {   // round-to-nearest-even
    unsigned int u = __float_as_uint(f);
    u += 0x7FFFu + ((u >> 16) & 1u);
    return (unsigned short)(u >> 16);
}

// ---------------------------------------------------------------------------
// Pose math (runs on ONE thread per block, result LDS-broadcast).
// Produces M (seg = M @ [u,v,1]), src.
// ---------------------------------------------------------------------------
__device__ inline void invert4x4(const float* m, float* inv) {
    inv[0]  =  m[5]*m[10]*m[15] - m[5]*m[11]*m[14] - m[9]*m[6]*m[15] + m[9]*m[7]*m[14] + m[13]*m[6]*m[11] - m[13]*m[7]*m[10];
    inv[4]  = -m[4]*m[10]*m[15] + m[4]*m[11]*m[14] + m[8]*m[6]*m[15] - m[8]*m[7]*m[14] - m[12]*m[6]*m[11] + m[12]*m[7]*m[10];
    inv[8]  =  m[4]*m[9]*m[15]  - m[4]*m[11]*m[13] - m[8]*m[5]*m[15] + m[8]*m[7]*m[13] + m[12]*m[5]*m[11] - m[12]*m[7]*m[9];
    inv[12] = -m[4]*m[9]*m[14]  + m[4]*m[10]*m[13] + m[8]*m[5]*m[14] - m[8]*m[6]*m[13] - m[12]*m[5]*m[10] + m[12]*m[6]*m[9];
    inv[1]  = -m[1]*m[10]*m[15] + m[1]*m[11]*m[14] + m[9]*m[2]*m[15] - m[9]*m[3]*m[14] - m[13]*m[2]*m[11] + m[13]*m[3]*m[10];
    inv[5]  =  m[0]*m[10]*m[15] - m[0]*m[11]*m[14] - m[8]*m[2]*m[15] + m[8]*m[3]*m[14] + m[12]*m[2]*m[11] - m[12]*m[3]*m[10];
    inv[9]  = -m[0]*m[9]*m[15]  + m[0]*m[11]*m[13] + m[8]*m[1]*m[15] - m[8]*m[3]*m[13] - m[12]*m[1]*m[11] + m[12]*m[3]*m[9];
    inv[13] =  m[0]*m[9]*m[14]  - m[0]*m[10]*m[13] - m[8]*m[1]*m[14] + m[8]*m[2]*m[13] + m[12]*m[1]*m[10] - m[12]*m[2]*m[9];
    inv[2]  =  m[1]*m[6]*m[15]  - m[1]*m[7]*m[14]  - m[5]*m[2]*m[15] + m[5]*m[3]*m[14] + m[13]*m[2]*m[7]  - m[13]*m[3]*m[6];
    inv[6]  = -m[0]*m[6]*m[15]  + m[0]*m[7]*m[14]  + m[4]*m[2]*m[15] - m[4]*m[3]*m[14] - m[12]*m[2]*m[7]  + m[12]*m[3]*m[6];
    inv[10] =  m[0]*m[5]*m[15]  - m[0]*m[7]*m[13]  - m[4]*m[1]*m[15] + m[4]*m[3]*m[13] + m[12]*m[1]*m[7]  - m[12]*m[3]*m[5];
    inv[14] = -m[0]*m[5]*m[14]  + m[0]*m[6]*m[13]  + m[4]*m[1]*m[14] - m[4]*m[2]*m[13] - m[12]*m[1]*m[6]  + m[12]*m[2]*m[5];
    inv[3]  = -m[1]*m[6]*m[11]  + m[1]*m[7]*m[10]  + m[5]*m[2]*m[11] - m[5]*m[3]*m[10] - m[9]*m[2]*m[7]   + m[9]*m[3]*m[6];
    inv[7]  =  m[0]*m[6]*m[11]  - m[0]*m[7]*m[10]  - m[4]*m[2]*m[11] + m[4]*m[3]*m[10] + m[8]*m[2]*m[7]   - m[8]*m[3]*m[6];
    inv[11] = -m[0]*m[5]*m[11]  + m[0]*m[7]*m[9]   + m[4]*m[1]*m[11] - m[4]*m[3]*m[9]  - m[8]*m[1]*m[7]   + m[8]*m[3]*m[5];
    inv[15] =  m[0]*m[5]*m[10]  - m[0]*m[6]*m[9]   - m[4]*m[1]*m[10] + m[4]*m[2]*m[9]  + m[8]*m[1]*m[6]   - m[8]*m[2]*m[5];
    float det = m[0]*inv[0] + m[1]*inv[4] + m[2]*inv[8] + m[3]*inv[12];
    float rdet = 1.0f / det;
    for (int i = 0; i < 16; i++) inv[i] *= rdet;
}

__device__ inline void compute_pose(const float* __restrict__ iso,
                                    const float* __restrict__ rt,
                                    const float* __restrict__ kinv,
                                    const float* __restrict__ sdd,
                                    const float* __restrict__ rot,
                                    const float* __restrict__ xyz,
                                    float* M, float* src3) {
    float m[16];
    for (int i = 0; i < 16; i++) m[i] = rt[i];
    float minv[16];
    invert4x4(m, minv);
    float c0 = minv[0]*iso[0] + minv[1]*iso[1] + minv[2]*iso[2]  + minv[3];
    float c1 = minv[4]*iso[0] + minv[5]*iso[1] + minv[6]*iso[2]  + minv[7];
    float c2 = minv[8]*iso[0] + minv[9]*iso[1] + minv[10]*iso[2] + minv[11];
    float wx = rot[0], wy = rot[1], wz = rot[2];
    float th2 = wx*wx + wy*wy + wz*wz;
    float th = sqrtf(th2);
    float Ac, Bc;
    if (th < 1e-6f) { Ac = 1.0f - th2 / 6.0f; Bc = 0.5f - th2 / 24.0f; }
    else            { Ac = sinf(th) / th;     Bc = (1.0f - cosf(th)) / th2; }
    float R[9];
    R[0] = 1.0f + Bc * (-(wy*wy + wz*wz));
    R[1] = Ac * (-wz) + Bc * (wx*wy);
    R[2] = Ac * ( wy) + Bc * (wx*wz);
    R[3] = Ac * ( wz) + Bc * (wx*wy);
    R[4] = 1.0f + Bc * (-(wx*wx + wz*wz));
    R[5] = Ac * (-wx) + Bc * (wy*wz);
    R[6] = Ac * (-wy) + Bc * (wx*wz);
    R[7] = Ac * ( wx) + Bc * (wy*wz);
    R[8] = 1.0f + Bc * (-(wx*wx + wy*wy));
    float tx = R[0]*xyz[0] + R[1]*xyz[1] + R[2]*xyz[2];
    float ty = R[3]*xyz[0] + R[4]*xyz[1] + R[5]*xyz[2];
    float tz = R[6]*xyz[0] + R[7]*xyz[1] + R[8]*xyz[2];
    float pt0 = c0 + tx - (R[0]*c0 + R[1]*c1 + R[2]*c2);
    float pt1 = c1 + ty - (R[3]*c0 + R[4]*c1 + R[5]*c2);
    float pt2 = c2 + tz - (R[6]*c0 + R[7]*c1 + R[8]*c2);
    float E[12];
    for (int i = 0; i < 3; i++) {
        for (int j = 0; j < 3; j++)
            E[i*4+j] = rt[i*4+0]*R[0*3+j] + rt[i*4+1]*R[1*3+j] + rt[i*4+2]*R[2*3+j];
        E[i*4+3] = rt[i*4+0]*pt0 + rt[i*4+1]*pt1 + rt[i*4+2]*pt2 + rt[i*4+3];
    }
    float s = sdd[0];
    for (int i = 0; i < 3; i++)
        for (int j = 0; j < 3; j++)
            M[i*3+j] = s * (E[i*4+0]*kinv[0*3+j] + E[i*4+1]*kinv[1*3+j] + E[i*4+2]*kinv[2*3+j]);
    src3[0] = E[3]; src3[1] = E[7]; src3[2] = E[11];
}

// ---------------------------------------------------------------------------
// Transpose: Tp[z][y][x] = (bf16 vol[x][y][z]) | (bf16 vol[x+1][y][z] << 16)
// Thread 0 computes the sampled-voxel AABB inline; tiles fully outside skip.
// grid = (4 x-tiles, 8 z-tiles, 256 y), block = 256
// ---------------------------------------------------------------------------
__global__ __launch_bounds__(256)
void transpose_k(const float* __restrict__ in, unsigned int* __restrict__ Tp,
                 const float* __restrict__ iso, const float* __restrict__ rt,
                 const float* __restrict__ kinv, const float* __restrict__ sdd,
                 const float* __restrict__ rot, const float* __restrict__ xyz,
                 const int* __restrict__ pH, const int* __restrict__ pW) {
    __shared__ int B[6];
    __shared__ unsigned short tile[32][72];   // 144B rows -> 8B-aligned b64 reads
    const int t = threadIdx.x;
    if (t == 0) {
        float M[9], src3[3];
        compute_pose(iso, rt, kinv, sdd, rot, xyz, M, src3);
        float W = (float)pW[0], H = (float)pH[0];
        float us[2] = {0.5f, W - 0.5f};
        float vs[2] = {0.5f, H - 0.5f};
        for (int a = 0; a < 3; a++) {
            float gmin = 1e30f, gmax = -1e30f;
            for (int i = 0; i < 2; i++)
                for (int j = 0; j < 2; j++) {
                    float g = M[a*3+0]*us[i] + M[a*3+1]*vs[j] + M[a*3+2];
                    gmin = fminf(gmin, g); gmax = fmaxf(gmax, g);
                }
            float sa = src3[a];
            int loi = (int)floorf(sa + fminf(0.0f, gmin)) - 4;
            int hii = (int)ceilf (sa + fmaxf(0.0f, gmax)) + 5;
            B[2*a]   = min(max(loi, 0), VD - 1);
            B[2*a+1] = min(max(hii, 0), VD - 1);
        }
    }
    __syncthreads();
    const int x0 = blockIdx.x * 64;
    const int z0 = blockIdx.y * 32;
    const int y  = blockIdx.z;
    // Skipped tiles are never read with nonzero weight; zero-weight reads of
    // poison are finite and multiply to exactly 0.
    if (x0 + 63 < B[0] || x0 > B[1] || y < B[2] || y > B[3] ||
        z0 + 31 < B[4] || z0 > B[5]) return;

    {
        const int zq = t & 7;          // float4 slot along z
        const int xl = t >> 3;         // 0..31
        #pragma unroll
        for (int i = 0; i < 2; i++) {
            int xr = xl + 32 * i;      // 0..63
            const float4 f = *(const float4*)(in + (((size_t)(x0 + xr)) << 16) + (y << 8) + z0 + 4*zq);
            tile[4*zq+0][xr] = f2bf(f.x);
            tile[4*zq+1][xr] = f2bf(f.y);
            tile[4*zq+2][xr] = f2bf(f.z);
            tile[4*zq+3][xr] = f2bf(f.w);
        }
        if (t < 8) {                   // halo row x0+64 (clamped)
            int xs = min(x0 + 64, VD - 1);
            const float4 f = *(const float4*)(in + (((size_t)xs) << 16) + (y << 8) + z0 + 4*t);
            tile[4*t+0][64] = f2bf(f.x);
            tile[4*t+1][64] = f2bf(f.y);
            tile[4*t+2][64] = f2bf(f.z);
            tile[4*t+3][64] = f2bf(f.w);
        }
    }
    __syncthreads();
    {
        const int xq = t & 15;         // 4-x group
        const int zl = t >> 4;         // 0..15
        #pragma unroll
        for (int i = 0; i < 2; i++) {
            int zr = zl + 16 * i;      // 0..31
            const uint2 aa = *reinterpret_cast<const uint2*>(&tile[zr][4*xq]);  // 8B aligned
            unsigned int a0 = aa.x & 0xFFFFu, a1 = aa.x >> 16;
            unsigned int a2 = aa.y & 0xFFFFu, a3 = aa.y >> 16;
            unsigned int a4 = tile[zr][4*xq+4];
            uint4 o;
            o.x = a0 | (a1 << 16);
            o.y = a1 | (a2 << 16);
            o.z = a2 | (a3 << 16);
            o.w = a3 | (a4 << 16);
            *(uint4*)(Tp + (((size_t)(z0 + zr)) << 16) + (y << 8) + x0 + 4*xq) = o;
        }
    }
}

// ---------------------------------------------------------------------------
// Render from paired layout, interior fast path + guarded edge path.
// ---------------------------------------------------------------------------
__device__ inline float sample_guarded(const unsigned int* __restrict__ Tp,
                                       float x, float y, float z) {
    float fx = floorf(x); int ix = (int)fx; float ax = x - fx;
    float fy = floorf(y); int iy = (int)fy; float ay = y - fy;
    float fz = floorf(z); int iz = (int)fz; float az = z - fz;

    float wx0v = ((unsigned)ix       < (unsigned)VD) ? (1.0f - ax) : 0.0f;
    float wx1v = ((unsigned)(ix + 1) < (unsigned)VD) ? ax : 0.0f;
    int bx = min(max(ix, 0), VD - 1);
    int sxi = ix - bx;                 // 0 interior, -1 left edge, else OOB
    float w0p = (sxi == 0) ? wx0v : ((sxi == -1) ? wx1v : 0.0f);
    float w1p = (sxi == 0) ? wx1v : 0.0f;

    float wy0 = ((unsigned)iy       < (unsigned)VD) ? (1.0f - ay) : 0.0f;
    float wy1 = ((unsigned)(iy + 1) < (unsigned)VD) ? ay : 0.0f;
    float wz0 = ((unsigned)iz       < (unsigned)VD) ? (1.0f - az) : 0.0f;
    float wz1 = ((unsigned)(iz + 1) < (unsigned)VD) ? az : 0.0f;

    int iy0 = min(max(iy, 0), VD - 1), iy1 = min(max(iy + 1, 0), VD - 1);
    int iz0 = min(max(iz, 0), VD - 1), iz1 = min(max(iz + 1, 0), VD - 1);

    int i00 = (iz0 << 16) + (iy0 << 8) + bx;
    int i01 = i00 + ((iy1 - iy0) << 8);
    int i10 = i00 + ((iz1 - iz0) << 16);
    int i11 = i10 + ((iy1 - iy0) << 8);

    unsigned int p00 = Tp[i00];
    unsigned int p01 = Tp[i01];
    unsigned int p10 = Tp[i10];
    unsigned int p11 = Tp[i11];

    float f00a = __uint_as_float(p00 << 16), f00b = __uint_as_float(p00 & 0xFFFF0000u);
    float f01a = __uint_as_float(p01 << 16), f01b = __uint_as_float(p01 & 0xFFFF0000u);
    float f10a = __uint_as_float(p10 << 16), f10b = __uint_as_float(p10 & 0xFFFF0000u);
    float f11a = __uint_as_float(p11 << 16), f11b = __uint_as_float(p11 & 0xFFFF0000u);

    float cx00 = fmaf(f00a, w0p, f00b * w1p);
    float cx01 = fmaf(f01a, w0p, f01b * w1p);
    float cx10 = fmaf(f10a, w0p, f10b * w1p);
    float cx11 = fmaf(f11a, w0p, f11b * w1p);

    float cy0 = fmaf(cx00, wy0, cx01 * wy1);
    float cy1 = fmaf(cx10, wy0, cx11 * wy1);
    return cy0 * wz0 + cy1 * wz1;
}

__global__ __launch_bounds__(256)
void render_pair(const unsigned int* __restrict__ Tp,
                 const float* __restrict__ iso, const float* __restrict__ rt,
                 const float* __restrict__ kinv, const float* __restrict__ sdd,
                 const float* __restrict__ rot, const float* __restrict__ xyz,
                 const int* __restrict__ pW, const int* __restrict__ pN,
                 float* __restrict__ out, int total) {
    __shared__ float S[12];
    if (threadIdx.x == 0) {
        float M[9], src3[3];
        compute_pose(iso, rt, kinv, sdd, rot, xyz, M, src3);
        for (int i = 0; i < 9; i++) S[i] = M[i];
        S[9] = src3[0]; S[10] = src3[1]; S[11] = src3[2];
    }
    __syncthreads();
    int tid = blockIdx.x * 256 + threadIdx.x;
    if (tid >= total) return;
    const int W = pW[0];
    const int N = pN[0];
    int w = tid % W;
    int h = tid / W;
    float u = (float)w + 0.5f;
    float v = (float)h + 0.5f;

    float gx = S[0]*u + S[1]*v + S[2];
    float gy = S[3]*u + S[4]*v + S[5];
    float gz = S[6]*u + S[7]*v + S[8];
    float sx = S[9], sy = S[10], sz = S[11];
    float len = sqrtf(gx*gx + gy*gy + gz*gz);
    float invN = 1.0f / (float)N;

    // Support clip (coord in (-1, VD)); weights still gate correctness.
    float t0 = 0.0f, t1 = 1.0f;
    // Interior clip (all 8 corners in-bounds guaranteed): coord in [0, VD-1-eps]
    float tA = 0.0f, tB = 1.0f;
    {
        const float HI = (float)(VD - 1) - 0.01f;
        float s3[3] = {sx, sy, sz};
        float g3[3] = {gx, gy, gz};
        for (int a = 0; a < 3; a++) {
            float g = g3[a], s = s3[a];
            if (fabsf(g) > 1e-20f) {
                float rg = 1.0f / g;
                float ta = (-1.0f - s) * rg;
                float tb = ((float)VD - s) * rg;
                t0 = fmaxf(t0, fminf(ta, tb));
                t1 = fminf(t1, fmaxf(ta, tb));
                float tc = (0.0f - s) * rg;
                float td = (HI - s) * rg;
                tA = fmaxf(tA, fminf(tc, td));
                tB = fminf(tB, fmaxf(tc, td));
            } else {
                if (s <= -1.0f || s >= (float)VD) t1 = -1.0f;
                if (s < 0.0f || s > HI)           tB = -2.0f;
            }
        }
    }
    int k0 = (int)floorf(t0 * (float)N - 0.5f) - 1;
    int k1 = (int)ceilf (t1 * (float)N - 0.5f) + 1;
    if (k0 < 0) k0 = 0;
    if (k1 > N - 1) k1 = N - 1;
    int kA = (int)ceilf (tA * (float)N - 0.5f) + 1;
    int kB = (int)floorf(tB * (float)N - 0.5f) - 1;
    kA = max(kA, k0);
    kB = min(kB, k1);

    float acc = 0.0f;
    // guarded head: [k0, min(kA-1, k1)]
    int headEnd = min(kA - 1, k1);
    for (int k = k0; k <= headEnd; k++) {
        float t = ((float)k + 0.5f) * invN;
        acc += sample_guarded(Tp, fmaf(t, gx, sx), fmaf(t, gy, sy), fmaf(t, gz, sz));
    }
    // fast interior: [kA, kB] — no bounds logic at all
    #pragma unroll 2
    for (int k = kA; k <= kB; k++) {
        float t = ((float)k + 0.5f) * invN;
        float x = fmaf(t, gx, sx);
        float y = fmaf(t, gy, sy);
        float z = fmaf(t, gz, sz);
        float fx = floorf(x); int ix = (int)fx; float ax = x - fx;
        float fy = floorf(y); int iy = (int)fy; float ay = y - fy;
        float fz = floorf(z); int iz = (int)fz; float az = z - fz;
        int idx = (iz << 16) + (iy << 8) + ix;
        unsigned int p00 = Tp[idx];
        unsigned int p01 = Tp[idx + 256];
        unsigned int p10 = Tp[idx + 65536];
        unsigned int p11 = Tp[idx + 65536 + 256];
        float f00a = __uint_as_float(p00 << 16), f00b = __uint_as_float(p00 & 0xFFFF0000u);
        float f01a = __uint_as_float(p01 << 16), f01b = __uint_as_float(p01 & 0xFFFF0000u);
        float f10a = __uint_as_float(p10 << 16), f10b = __uint_as_float(p10 & 0xFFFF0000u);
        float f11a = __uint_as_float(p11 << 16), f11b = __uint_as_float(p11 & 0xFFFF0000u);
        float cx00 = fmaf(f00b - f00a, ax, f00a);
        float cx01 = fmaf(f01b - f01a, ax, f01a);
        float cx10 = fmaf(f10b - f10a, ax, f10a);
        float cx11 = fmaf(f11b - f11a, ax, f11a);
        float cy0 = fmaf(cx01 - cx00, ay, cx00);
        float cy1 = fmaf(cx11 - cx10, ay, cx10);
        acc += fmaf(cy1 - cy0, az, cy0);
    }
    // guarded tail: [max(kB+1, kA), k1]
    int tailStart = max(kB + 1, kA);
    for (int k = tailStart; k <= k1; k++) {
        float t = ((float)k + 0.5f) * invN;
        acc += sample_guarded(Tp, fmaf(t, gx, sx), fmaf(t, gy, sy), fmaf(t, gz, sz));
    }
    out[tid] = acc * len * invN;
}

// ---------------------------------------------------------------------------
// Fallback: direct fp32 render from original layout (if ws too small).
// ---------------------------------------------------------------------------
__global__ __launch_bounds__(256)
void render_direct(const float* __restrict__ vol,
                   const float* __restrict__ iso, const float* __restrict__ rt,
                   const float* __restrict__ kinv, const float* __restrict__ sdd,
                   const float* __restrict__ rot, const float* __restrict__ xyz,
                   const int* __restrict__ pW, const int* __restrict__ pN,
                   float* __restrict__ out, int total) {
    __shared__ float S[12];
    if (threadIdx.x == 0) {
        float M[9], src3[3];
        compute_pose(iso, rt, kinv, sdd, rot, xyz, M, src3);
        for (int i = 0; i < 9; i++) S[i] = M[i];
        S[9] = src3[0]; S[10] = src3[1]; S[11] = src3[2];
    }
    __syncthreads();
    int tid = blockIdx.x * 256 + threadIdx.x;
    if (tid >= total) return;
    const int W = pW[0];
    const int N = pN[0];
    int w = tid % W;
    int h = tid / W;
    float u = (float)w + 0.5f;
    float v = (float)h + 0.5f;
    float gx = S[0]*u + S[1]*v + S[2];
    float gy = S[3]*u + S[4]*v + S[5];
    float gz = S[6]*u + S[7]*v + S[8];
    float sx = S[9], sy = S[10], sz = S[11];
    float len = sqrtf(gx*gx + gy*gy + gz*gz);
    float invN = 1.0f / (float)N;
    float acc = 0.0f;
    for (int k = 0; k < N; k++) {
        float t = ((float)k + 0.5f) * invN;
        float x = fmaf(t, gx, sx);
        float y = fmaf(t, gy, sy);
        float z = fmaf(t, gz, sz);
        float fx = floorf(x); int ix = (int)fx; float ax = x - fx;
        float fy = floorf(y); int iy = (int)fy; float ay = y - fy;
        float fz = floorf(z); int iz = (int)fz; float az = z - fz;
        float wx0 = ((unsigned)ix       < (unsigned)VD) ? (1.0f - ax) : 0.0f;
        float wx1 = ((unsigned)(ix + 1) < (unsigned)VD) ? ax : 0.0f;
        float wy0 = ((unsigned)iy       < (unsigned)VD) ? (1.0f - ay) : 0.0f;
        float wy1 = ((unsigned)(iy + 1) < (unsigned)VD) ? ay : 0.0f;
        float wz0 = ((unsigned)iz       < (unsigned)VD) ? (1.0f - az) : 0.0f;
        float wz1 = ((unsigned)(iz + 1) < (unsigned)VD) ? az : 0.0f;
        int ix0 = min(max(ix, 0), VD - 1), ix1 = min(max(ix + 1, 0), VD - 1);
        int iy0 = min(max(iy, 0), VD - 1), iy1 = min(max(iy + 1, 0), VD - 1);
        int iz0 = min(max(iz, 0), VD - 1), iz1 = min(max(iz + 1, 0), VD - 1);
        int X0 = ix0 << 16, X1 = ix1 << 16;
        int Y0 = iy0 << 8,  Y1 = iy1 << 8;
        float v000 = vol[X0 + Y0 + iz0];
        float v001 = vol[X0 + Y0 + iz1];
        float v010 = vol[X0 + Y1 + iz0];
        float v011 = vol[X0 + Y1 + iz1];
        float v100 = vol[X1 + Y0 + iz0];
        float v101 = vol[X1 + Y0 + iz1];
        float v110 = vol[X1 + Y1 + iz0];
        float v111 = vol[X1 + Y1 + iz1];
        float c00 = fmaf(v000, wz0, v001 * wz1);
        float c01 = fmaf(v010, wz0, v011 * wz1);
        float c10 = fmaf(v100, wz0, v101 * wz1);
        float c11 = fmaf(v110, wz0, v111 * wz1);
        float c0  = fmaf(c00, wy0, c01 * wy1);
        float c1  = fmaf(c10, wy0, c11 * wy1);
        acc += fmaf(c0, wx0, c1 * wx1);
    }
    out[tid] = acc * len * invN;
}

extern "C" void kernel_launch(void* const* d_in, const int* in_sizes, int n_in,
                              void* d_out, int out_size, void* d_ws, size_t ws_size,
                              hipStream_t stream) {
    const float* vol  = (const float*)d_in[0];
    const float* iso  = (const float*)d_in[1];
    const float* rt   = (const float*)d_in[2];
    const float* kinv = (const float*)d_in[3];
    const float* sdd  = (const float*)d_in[4];
    const float* rot  = (const float*)d_in[5];
    const float* xyz  = (const float*)d_in[6];
    const int* pH = (const int*)d_in[7];
    const int* pW = (const int*)d_in[8];
    const int* pN = (const int*)d_in[9];
    float* out = (float*)d_out;
    int total = out_size;

    if (ws_size >= PAIR_BYTES) {
        unsigned int* Tp = (unsigned int*)d_ws;
        transpose_k<<<dim3(4, 8, 256), 256, 0, stream>>>(vol, Tp, iso, rt, kinv, sdd, rot, xyz, pH, pW);
        render_pair<<<(total + 255) / 256, 256, 0, stream>>>(Tp, iso, rt, kinv, sdd, rot, xyz, pW, pN, out, total);
    } else {
        render_direct<<<(total + 255) / 256, 256, 0, stream>>>(vol, iso, rt, kinv, sdd, rot, xyz, pW, pN, out, total);
    }
}